// Round 9
// baseline (27.389 us; speedup 1.0000x reference)
//
#include <hip/hip_runtime.h>
#include <math.h>

#define B_   4
#define C_   32
#define H_   128
#define W_   128
#define HW_  (H_ * W_)
#define PAD_ 4
#define TW   16               /* tile width (px) */
#define TH   8                /* tile height (px) */
#define RW   (TW + 8)         /* 24 */
#define RH   (TH + 8)         /* 16 */
#define NPIX (RW * RH)        /* 384 */
#define NPADPIX (NPIX + RW)   /* 408: +1 zero row for masked tail reads */
#define SPC  5                /* pixel stride in 16B chunks = 80 B (conflict-benign) */
#define NSLOT (NPADPIX * SPC) /* 2040 */
#define NTHREADS 256          /* 4 threads per pixel-PAIR; 64 pairs = 128 px/block */

typedef _Float16 h2 __attribute__((ext_vector_type(2)));
typedef _Float16 h8 __attribute__((ext_vector_type(8)));
union h8v { h8 v; h2 h[4]; uint4 u; };

__device__ __forceinline__ float fdot2(h2 a, h2 b, float c) {
    return __builtin_amdgcn_fdot2(a, b, c, false);
}
__device__ __forceinline__ h2 shfl_xor_h2(h2 v, int m) {
    union { h2 h; int i; } u; u.h = v;
    u.i = __shfl_xor(u.i, m, 64);
    return u.h;
}

__global__ __launch_bounds__(NTHREADS, 2)
void soft_shift_align(const float* __restrict__ q,
                      const float* __restrict__ k,
                      float* __restrict__ out) {
    __shared__ h8 lds[NSLOT];   // 32640 B

    const int tid = threadIdx.x;
    const int x0  = blockIdx.x * TW;
    const int y0  = blockIdx.y * TH;
    const int b   = blockIdx.z;

    const float* kb = k + (size_t)b * C_ * HW_;
    const float* qb = q + (size_t)b * C_ * HW_;

    // ---- Stage normalized key region (zero halo + zero pad row) into LDS ----
    for (int rp = tid; rp < NPADPIX; rp += NTHREADS) {
        h8v o[4];
        bool valid = false;
        if (rp < NPIX) {
            const int ry = rp / RW;
            const int rx = rp - ry * RW;
            const int gy = y0 - PAD_ + ry;
            const int gx = x0 - PAD_ + rx;
            if (gy >= 0 && gy < H_ && gx >= 0 && gx < W_) {
                valid = true;
                float v[C_];
                float ss = 0.f;
                const float* p = kb + gy * W_ + gx;
                #pragma unroll
                for (int c = 0; c < C_; ++c) { v[c] = p[c * HW_]; ss += v[c] * v[c]; }
                const float inv = 1.f / fmaxf(sqrtf(ss), 1e-6f);
                #pragma unroll
                for (int i = 0; i < 4; ++i)
                    #pragma unroll
                    for (int j = 0; j < 8; ++j) o[i].v[j] = (_Float16)(v[i * 8 + j] * inv);
            }
        }
        if (!valid) {
            #pragma unroll
            for (int i = 0; i < 4; ++i) o[i].v = (h8)(_Float16)0.f;
        }
        uint4* dst = reinterpret_cast<uint4*>(lds) + rp * SPC;
        #pragma unroll
        for (int i = 0; i < 4; ++i) dst[i] = o[i].u;
    }

    // ---- Thread mapping: quad -> horizontal pixel pair (wx, wx+1) ----
    const int sub    = tid & 3;
    const int pairid = tid >> 2;       // 0..63
    const int pcol   = pairid & 7;     // 8 pairs = 16 px wide
    const int prow   = pairid >> 3;    // 0..7
    const int h      = y0 + prow;
    const int wx     = x0 + 2 * pcol;

    // Normalized q for BOTH pixels (float2 loads: adjacent in memory)
    h8v qv0[4], qv1[4];
    {
        float v0[C_], v1[C_];
        float s0 = 0.f, s1 = 0.f;
        const float2* p = reinterpret_cast<const float2*>(qb + h * W_ + wx);
        #pragma unroll
        for (int c = 0; c < C_; ++c) {
            const float2 t = p[c * (HW_ / 2)];
            v0[c] = t.x; v1[c] = t.y;
            s0 += t.x * t.x; s1 += t.y * t.y;
        }
        const float i0 = 1.f / fmaxf(sqrtf(s0), 1e-6f);
        const float i1 = 1.f / fmaxf(sqrtf(s1), 1e-6f);
        #pragma unroll
        for (int i = 0; i < 4; ++i)
            #pragma unroll
            for (int j = 0; j < 8; ++j) {
                qv0[i].v[j] = (_Float16)(v0[i * 8 + j] * i0);
                qv1[i].v[j] = (_Float16)(v1[i * 8 + j] * i1);
            }
    }

    __syncthreads();

    // ---- Walk the 9x10 union window; position p = 4*i + sub over row-major (r,c) ----
    const float K2 = 20.6099379f;   // (1/0.07) * log2(e)
    float l0 = 0.f, l1 = 0.f;
    h2 acc0[16], acc1[16];
    #pragma unroll
    for (int u = 0; u < 16; ++u) { acc0[u] = (h2)(_Float16)0.f; acc1[u] = (h2)(_Float16)0.f; }

    int cc = sub;                      // column within the 10-wide union row
    const h8* kp = &lds[(prow * RW + 2 * pcol + sub) * SPC];

    #pragma unroll
    for (int i = 0; i < 23; ++i) {
        const int p = i * 4 + sub;
        h8v kk[4];
        kk[0].v = kp[0]; kk[1].v = kp[1]; kk[2].v = kp[2]; kk[3].v = kp[3];

        float a0 = 0.f, b0 = 0.f, c0 = 0.f, d0 = 0.f;
        float a1 = 0.f, b1 = 0.f, c1 = 0.f, d1 = 0.f;
        #pragma unroll
        for (int u = 0; u < 4; ++u) {
            a0 = fdot2(kk[0].h[u], qv0[0].h[u], a0);
            b0 = fdot2(kk[1].h[u], qv0[1].h[u], b0);
            c0 = fdot2(kk[2].h[u], qv0[2].h[u], c0);
            d0 = fdot2(kk[3].h[u], qv0[3].h[u], d0);
            a1 = fdot2(kk[0].h[u], qv1[0].h[u], a1);
            b1 = fdot2(kk[1].h[u], qv1[1].h[u], b1);
            c1 = fdot2(kk[2].h[u], qv1[2].h[u], c1);
            d1 = fdot2(kk[3].h[u], qv1[3].h[u], d1);
        }
        const float dot0 = (a0 + b0) + (c0 + d0);
        const float dot1 = (a1 + b1) + (c1 + d1);

        // coverage masks: px0 uses cols 0..8, px1 uses cols 1..9; p>=90 is tail pad
        const float m0 = (cc <= 8 && p < 90) ? 1.f : 0.f;
        const float m1 = (cc >= 1 && p < 90) ? 1.f : 0.f;
        const float wg0 = exp2f(fmaf(dot0, K2, -K2)) * m0;
        const float wg1 = exp2f(fmaf(dot1, K2, -K2)) * m1;
        l0 += wg0; l1 += wg1;

        const _Float16 w0 = (_Float16)wg0, w1 = (_Float16)wg1;
        const h2 W0 = {w0, w0}, W1 = {w1, w1};
        #pragma unroll
        for (int u = 0; u < 4; ++u) {
            acc0[u]      = W0 * kk[0].h[u] + acc0[u];      // v_pk_fma_f16
            acc0[4 + u]  = W0 * kk[1].h[u] + acc0[4 + u];
            acc0[8 + u]  = W0 * kk[2].h[u] + acc0[8 + u];
            acc0[12 + u] = W0 * kk[3].h[u] + acc0[12 + u];
            acc1[u]      = W1 * kk[0].h[u] + acc1[u];
            acc1[4 + u]  = W1 * kk[1].h[u] + acc1[4 + u];
            acc1[8 + u]  = W1 * kk[2].h[u] + acc1[8 + u];
            acc1[12 + u] = W1 * kk[3].h[u] + acc1[12 + u];
        }

        if (i < 22) {                  // advance p -> p+4: wrap when col >= 6
            const bool wrap = (cc >= 6);
            kp += wrap ? (RW - 6) * SPC : 4 * SPC;
            cc  = wrap ? cc - 6 : cc + 4;
        }
    }

    // ---- Combine the 4 partials across the quad ----
    l0 += __shfl_xor(l0, 1, 64); l1 += __shfl_xor(l1, 1, 64);
    #pragma unroll
    for (int u = 0; u < 16; ++u) {
        acc0[u] = acc0[u] + shfl_xor_h2(acc0[u], 1);
        acc1[u] = acc1[u] + shfl_xor_h2(acc1[u], 1);
    }
    l0 += __shfl_xor(l0, 2, 64); l1 += __shfl_xor(l1, 2, 64);
    #pragma unroll
    for (int u = 0; u < 16; ++u) {
        acc0[u] = acc0[u] + shfl_xor_h2(acc0[u], 2);
        acc1[u] = acc1[u] + shfl_xor_h2(acc1[u], 2);
    }

    // ---- Each thread writes its 8 channels for both pixels (float2 stores) ----
    const float il0 = 1.f / l0, il1 = 1.f / l1;
    float* po = out + ((size_t)(b * C_ + sub * 8) * H_ + h) * W_ + wx;
    #pragma unroll
    for (int j = 0; j < 8; ++j) {
        const int u = sub * 4 + (j >> 1);
        float2 t;
        t.x = (float)acc0[u][j & 1] * il0;
        t.y = (float)acc1[u][j & 1] * il1;
        *reinterpret_cast<float2*>(po + j * HW_) = t;
    }
}

extern "C" void kernel_launch(void* const* d_in, const int* in_sizes, int n_in,
                              void* d_out, int out_size, void* d_ws, size_t ws_size,
                              hipStream_t stream) {
    const float* q = (const float*)d_in[0];
    const float* k = (const float*)d_in[1];
    float* out = (float*)d_out;
    dim3 grid(W_ / TW, H_ / TH, B_);
    soft_shift_align<<<grid, NTHREADS, 0, stream>>>(q, k, out);
}

// Round 10
// 25.780 us; speedup vs baseline: 1.0624x; 1.0624x over previous
//
#include <hip/hip_runtime.h>
#include <math.h>

#define B_   4
#define C_   32
#define H_   128
#define W_   128
#define HW_  (H_ * W_)
#define WIN_ 9
#define PAD_ 4
#define TW   16
#define TH   8
#define RW   (TW + WIN_ - 1)   /* 24 */
#define RH   (TH + WIN_ - 1)   /* 16 */
#define NPIX (RW * RH)         /* 384 */
#define SPC  5                 /* pixel stride in 16B chunks = 80B, coprime with 8 bank-groups */
#define NTHREADS 512           /* 4 threads per output pixel, 128 px/block */

typedef _Float16 h2 __attribute__((ext_vector_type(2)));
typedef _Float16 h8 __attribute__((ext_vector_type(8)));

union h8v { h8 v; h2 h[4]; uint4 u; };

__device__ __forceinline__ float fdot2(h2 a, h2 b, float c) {
    return __builtin_amdgcn_fdot2(a, b, c, false);
}

__device__ __forceinline__ h2 shfl_xor_h2(h2 v, int mask) {
    union { h2 h; int i; } u; u.h = v;
    u.i = __shfl_xor(u.i, mask, 64);
    return u.h;
}

__global__ __launch_bounds__(NTHREADS, 4)
void soft_shift_align(const float* __restrict__ q,
                      const float* __restrict__ k,
                      float* __restrict__ out) {
    __shared__ h8 lds[NPIX * SPC];   // 384 * 80 B = 30720 B

    const int tid = threadIdx.x;
    const int x0  = blockIdx.x * TW;
    const int y0  = blockIdx.y * TH;
    const int b   = blockIdx.z;

    const float* kb = k + (size_t)b * C_ * HW_;
    const float* qb = q + (size_t)b * C_ * HW_;

    // ---- Stage normalized key region (zero halo) into LDS as packed f16 ----
    if (tid < NPIX) {
        const int ry = tid / RW;
        const int rx = tid - ry * RW;
        const int gy = y0 - PAD_ + ry;
        const int gx = x0 - PAD_ + rx;
        h8 o[4];
        if (gy >= 0 && gy < H_ && gx >= 0 && gx < W_) {
            float v[C_];
            float ss = 0.f;
            const float* p = kb + gy * W_ + gx;
            #pragma unroll
            for (int c = 0; c < C_; ++c) { v[c] = p[c * HW_]; ss += v[c] * v[c]; }
            const float inv = 1.f / fmaxf(sqrtf(ss), 1e-6f);
            #pragma unroll
            for (int i = 0; i < 4; ++i)
                #pragma unroll
                for (int j = 0; j < 8; ++j) o[i][j] = (_Float16)(v[i * 8 + j] * inv);
        } else {
            #pragma unroll
            for (int i = 0; i < 4; ++i) o[i] = (h8)(_Float16)0.f;
        }
        #pragma unroll
        for (int i = 0; i < 4; ++i) lds[tid * SPC + i] = o[i];
    }

    // ---- This thread: pixel px, position-subset sub (p = 4i + sub) ----
    const int px  = tid >> 2;
    const int sub = tid & 3;
    const int tx  = px & (TW - 1);
    const int ty  = px >> 4;
    const int h   = y0 + ty;
    const int w   = x0 + tx;

    // Full normalized query in registers (all 32 ch per thread; L1/L2-served)
    h2 qv[16];
    {
        float v[C_];
        float ss = 0.f;
        const float* p = qb + h * W_ + w;
        #pragma unroll
        for (int c = 0; c < C_; ++c) { v[c] = p[c * HW_]; ss += v[c] * v[c]; }
        const float inv = 1.f / fmaxf(sqrtf(ss), 1e-6f);
        #pragma unroll
        for (int u = 0; u < 16; ++u) {
            qv[u][0] = (_Float16)(v[2*u]     * inv);
            qv[u][1] = (_Float16)(v[2*u + 1] * inv);
        }
    }

    __syncthreads();

    // ---- Softmax-weighted aggregation over this thread's ~20 positions ----
    const float invT = 1.0f / 0.07f;
    h2 acc[16];
    #pragma unroll
    for (int u = 0; u < 16; ++u) acc[u] = (h2)(_Float16)0.f;
    float l = 0.f;

    #pragma unroll
    for (int i = 0; i < 21; ++i) {
        const int p = i * 4 + sub;
        if (p <= 80) {                       // only i==20 is partial (sub!=0 idle)
            const int dy = (p * 57) >> 9;    // floor(p/9) for p in [0,80]
            const int dx = p - dy * 9;
            const h8* kp = &lds[((ty + dy) * RW + (tx + dx)) * SPC];
            h8v kk[4];
            kk[0].v = kp[0]; kk[1].v = kp[1]; kk[2].v = kp[2]; kk[3].v = kp[3];

            float dA = 0.f, dB = 0.f, dC = 0.f, dD = 0.f;
            #pragma unroll
            for (int u = 0; u < 4; ++u) {
                dA = fdot2(kk[0].h[u], qv[u],      dA);
                dB = fdot2(kk[1].h[u], qv[4 + u],  dB);
                dC = fdot2(kk[2].h[u], qv[8 + u],  dC);
                dD = fdot2(kk[3].h[u], qv[12 + u], dD);
            }
            const float dot = (dA + dB) + (dC + dD);
            const float wg = __expf(fmaf(dot, invT, -invT));  // exp(sim - 1/T) in (0,1]
            l += wg;
            const _Float16 wh = (_Float16)wg;
            const h2 wgh = {wh, wh};
            #pragma unroll
            for (int u = 0; u < 4; ++u) {
                acc[u]      = wgh * kk[0].h[u] + acc[u];       // v_pk_fma_f16
                acc[4 + u]  = wgh * kk[1].h[u] + acc[4 + u];
                acc[8 + u]  = wgh * kk[2].h[u] + acc[8 + u];
                acc[12 + u] = wgh * kk[3].h[u] + acc[12 + u];
            }
        }
    }

    // ---- Combine the 4 partial (l, acc) across the pixel's thread quad (xor 1,2 -> DPP) ----
    l += __shfl_xor(l, 1, 64);
    #pragma unroll
    for (int u = 0; u < 16; ++u) acc[u] = acc[u] + shfl_xor_h2(acc[u], 1);
    l += __shfl_xor(l, 2, 64);
    #pragma unroll
    for (int u = 0; u < 16; ++u) acc[u] = acc[u] + shfl_xor_h2(acc[u], 2);

    // ---- Each thread writes its 8 channels ----
    const float invl = 1.f / l;
    float* po = out + ((size_t)(b * C_ + sub * 8) * H_ + h) * W_ + w;
    #pragma unroll
    for (int j = 0; j < 8; ++j) {
        const int u = sub * 4 + (j >> 1);
        po[j * HW_] = (float)acc[u][j & 1] * invl;
    }
}

extern "C" void kernel_launch(void* const* d_in, const int* in_sizes, int n_in,
                              void* d_out, int out_size, void* d_ws, size_t ws_size,
                              hipStream_t stream) {
    const float* q = (const float*)d_in[0];
    const float* k = (const float*)d_in[1];
    float* out = (float*)d_out;
    dim3 grid(W_ / TW, H_ / TH, B_);
    soft_shift_align<<<grid, NTHREADS, 0, stream>>>(q, k, out);
}